// Round 1
// baseline (198.285 us; speedup 1.0000x reference)
//
#include <hip/hip_runtime.h>
#include <hip/hip_fp16.h>

#define S_DIM 512
#define B_DIM 256
#define H_DIM 500
#define HP    512                 // padded H (both N and K of big GEMM)
#define M_DIM (S_DIM * B_DIM)     // 131072

typedef _Float16 half8_t __attribute__((ext_vector_type(8)));
typedef float    f32x4  __attribute__((ext_vector_type(4)));

// workspace layout (bytes)
#define WS_W2H 0                       // fp16 [512][512]  = 512 KB
#define WS_A   (512 * 1024)            // fp32 [256][512]  = 512 KB
#define WS_VP  (1024 * 1024)           // fp32 [512]       =   2 KB
#define WS_SC  (1024 * 1024 + 4096)    // fp32 [256][512]  = 512 KB (scores^T)

// ---- prep: W2 -> fp16 padded [512][512], v -> padded fp32[512] ----
__global__ void prep_w2_v(const float* __restrict__ W, const float* __restrict__ v,
                          _Float16* __restrict__ W2h, float* __restrict__ vp) {
    int idx = blockIdx.x * blockDim.x + threadIdx.x;   // 0..131071
#pragma unroll
    for (int r = 0; r < 2; ++r) {
        int e = idx + r * 131072;
        int h = e >> 9, k = e & 511;
        float val = (h < H_DIM && k < H_DIM) ? W[h * 1000 + 500 + k] : 0.0f;
        W2h[e] = (_Float16)val;
    }
    if (idx < HP) vp[idx] = (idx < H_DIM) ? v[idx] : 0.0f;
}

// ---- prep: A[b][h] = b_attn[h] + hidden[b,:] . W1[h,:]  (exact fp32) ----
__global__ void prep_A(const float* __restrict__ hidden, const float* __restrict__ W,
                       const float* __restrict__ b_attn, float* __restrict__ A) {
    int b = blockIdx.x;
    int t = threadIdx.x;               // 0..511
    __shared__ float hs[HP];
    hs[t] = (t < H_DIM) ? hidden[b * H_DIM + t] : 0.0f;
    __syncthreads();
    float acc = 0.0f;
    if (t < H_DIM) {
        acc = b_attn[t];
        const float4* wr = (const float4*)(W + t * 1000);  // W1 row h=t (1000 floats/row, 16B-aligned)
        const float4* hr = (const float4*)hs;
#pragma unroll 5
        for (int i = 0; i < 125; ++i) {
            float4 w4 = wr[i], h4 = hr[i];
            acc += w4.x * h4.x + w4.y * h4.y + w4.z * h4.z + w4.w * h4.w;
        }
    }
    A[b * HP + t] = acc;
}

// ---- main fused kernel: E = enc @ W2^T (f16 MFMA), scores = sum_h v*tanh(A+E) ----
__launch_bounds__(512, 2)
__global__ void fused_attn_gemm(const float* __restrict__ enc,
                                const _Float16* __restrict__ W2h,
                                const float* __restrict__ Aws,
                                const float* __restrict__ vp,
                                float* __restrict__ scores_t) {
    __shared__ _Float16 As[2][128][32];   // 16 KB
    __shared__ _Float16 Bs[2][HP][32];    // 64 KB
    __shared__ float    red[4][128];      //  2 KB

    const int tid  = threadIdx.x;
    const int lane = tid & 63;
    const int wid  = tid >> 6;
    const int wm   = wid >> 2;        // 0..1  (M half)
    const int wn   = wid & 3;         // 0..3  (N quarter)
    const int l15  = lane & 15;
    const int lq   = lane >> 4;       // 0..3
    const int m0   = blockIdx.x * 128;

    const int srow = tid >> 2;          // 0..127
    const int sc0  = (tid & 3) * 8;     // 0,8,16,24

    f32x4 acc[4][8];
#pragma unroll
    for (int a = 0; a < 4; ++a)
#pragma unroll
        for (int b = 0; b < 8; ++b) acc[a][b] = 0;

    auto stage = [&](int buf, int kk) {
        // A tile: 128 rows x 32 k (fp32 -> fp16), 8 halves/thread
        {
            const float* g = enc + (size_t)(m0 + srow) * H_DIM;
            half8_t hv;
            if (kk + sc0 + 8 <= H_DIM) {
                float4 f0 = *(const float4*)(g + kk + sc0);
                float4 f1 = *(const float4*)(g + kk + sc0 + 4);
                hv[0] = (_Float16)f0.x; hv[1] = (_Float16)f0.y;
                hv[2] = (_Float16)f0.z; hv[3] = (_Float16)f0.w;
                hv[4] = (_Float16)f1.x; hv[5] = (_Float16)f1.y;
                hv[6] = (_Float16)f1.z; hv[7] = (_Float16)f1.w;
            } else {
#pragma unroll
                for (int u = 0; u < 8; ++u) {
                    int k = kk + sc0 + u;
                    hv[u] = (k < H_DIM) ? (_Float16)g[k] : (_Float16)0.0f;
                }
            }
            *(half8_t*)&As[buf][srow][sc0] = hv;
        }
        // B tile: 512 rows x 32 k from fp16 W2h (L2-resident), 4 rows/thread
#pragma unroll
        for (int r = 0; r < 4; ++r) {
            int row = srow + r * 128;
            half8_t hv = *(const half8_t*)(W2h + row * HP + kk + sc0);
            *(half8_t*)&Bs[buf][row][sc0] = hv;
        }
    };

    stage(0, 0);
#pragma unroll 2
    for (int ks = 0; ks < 16; ++ks) {
        int cur = ks & 1;
        __syncthreads();                         // staged data visible; prev reads done
        if (ks + 1 < 16) stage(cur ^ 1, (ks + 1) * 32);

        half8_t af[4], bf[8];
#pragma unroll
        for (int mf = 0; mf < 4; ++mf)
            af[mf] = *(const half8_t*)&As[cur][wm * 64 + mf * 16 + l15][lq * 8];
#pragma unroll
        for (int nf = 0; nf < 8; ++nf)
            bf[nf] = *(const half8_t*)&Bs[cur][wn * 128 + nf * 16 + l15][lq * 8];
#pragma unroll
        for (int mf = 0; mf < 4; ++mf)
#pragma unroll
            for (int nf = 0; nf < 8; ++nf)
                acc[mf][nf] = __builtin_amdgcn_mfma_f32_16x16x32_f16(af[mf], bf[nf], acc[mf][nf], 0, 0, 0);
    }

    // ---- epilogue: scores[m] += v[h]*tanh(A[b][h] + E) ----
    float vpv[8];
#pragma unroll
    for (int nf = 0; nf < 8; ++nf) vpv[nf] = vp[wn * 128 + nf * 16 + l15];

    const int bloc  = (blockIdx.x & 1) * 128 + wm * 64;   // local b base (m = s*256+b; 128-row block => fixed s)
    const int s_idx = blockIdx.x >> 1;

#pragma unroll
    for (int mf = 0; mf < 4; ++mf) {
        float pj[4] = {0, 0, 0, 0};
#pragma unroll
        for (int nf = 0; nf < 8; ++nf) {
            int h = wn * 128 + nf * 16 + l15;
#pragma unroll
            for (int j = 0; j < 4; ++j) {
                int b = bloc + mf * 16 + lq * 4 + j;       // C row = (lane>>4)*4 + reg
                float x = acc[mf][nf][j] + Aws[b * HP + h];
                float xc = fminf(fmaxf(x, -9.0f), 9.0f);
                float e  = __expf(2.0f * xc);
                float th = (e - 1.0f) / (e + 1.0f);
                pj[j] += vpv[nf] * th;
            }
        }
#pragma unroll
        for (int j = 0; j < 4; ++j) {
            float s = pj[j];
            s += __shfl_xor(s, 1); s += __shfl_xor(s, 2);
            s += __shfl_xor(s, 4); s += __shfl_xor(s, 8);
            if (l15 == 0) red[wn][wm * 64 + mf * 16 + lq * 4 + j] = s;
        }
    }
    __syncthreads();
    if (tid < 128) {
        float sc = red[0][tid] + red[1][tid] + red[2][tid] + red[3][tid];
        int b = (blockIdx.x & 1) * 128 + tid;
        scores_t[b * S_DIM + s_idx] = sc;
    }
}

// ---- softmax over S per b; out[b][0][s] ----
__global__ void softmax_rows(const float* __restrict__ scores_t, float* __restrict__ out) {
    int b = blockIdx.x;
    int t = threadIdx.x;           // 256 threads, 2 elems each
    int lane = t & 63, wid = t >> 6;
    float v0 = scores_t[b * S_DIM + t];
    float v1 = scores_t[b * S_DIM + t + 256];
    float m = fmaxf(v0, v1);
#pragma unroll
    for (int off = 1; off < 64; off <<= 1) m = fmaxf(m, __shfl_xor(m, off));
    __shared__ float sm[4], ss[4];
    if (lane == 0) sm[wid] = m;
    __syncthreads();
    m = fmaxf(fmaxf(sm[0], sm[1]), fmaxf(sm[2], sm[3]));
    float e0 = __expf(v0 - m), e1 = __expf(v1 - m);
    float sum = e0 + e1;
#pragma unroll
    for (int off = 1; off < 64; off <<= 1) sum += __shfl_xor(sum, off);
    if (lane == 0) ss[wid] = sum;
    __syncthreads();
    sum = ss[0] + ss[1] + ss[2] + ss[3];
    float inv = 1.0f / sum;
    out[b * S_DIM + t]       = e0 * inv;
    out[b * S_DIM + t + 256] = e1 * inv;
}

extern "C" void kernel_launch(void* const* d_in, const int* in_sizes, int n_in,
                              void* d_out, int out_size, void* d_ws, size_t ws_size,
                              hipStream_t stream) {
    const float* hidden = (const float*)d_in[0];
    const float* enc    = (const float*)d_in[1];
    const float* W      = (const float*)d_in[2];
    const float* b_attn = (const float*)d_in[3];
    const float* v      = (const float*)d_in[4];
    float* out = (float*)d_out;

    char* ws = (char*)d_ws;
    _Float16* W2h = (_Float16*)(ws + WS_W2H);
    float*    A   = (float*)(ws + WS_A);
    float*    vp  = (float*)(ws + WS_VP);
    float*    sct = (float*)(ws + WS_SC);

    prep_w2_v<<<512, 256, 0, stream>>>(W, v, W2h, vp);
    prep_A<<<256, 512, 0, stream>>>(hidden, W, b_attn, A);
    fused_attn_gemm<<<1024, 512, 0, stream>>>(enc, W2h, A, vp, sct);
    softmax_rows<<<256, 256, 0, stream>>>(sct, out);
}